// Round 2
// baseline (1507.757 us; speedup 1.0000x reference)
//
#include <hip/hip_runtime.h>
#include <hip/hip_bf16.h>

#define N_NODES 16384
#define EDGE_CAP 256

// ---------------------------------------------------------------------------
// Generic linear layer: out[r, o] = act(sum_k in[r, k] * W[k, o] + b[o])
// 4 rows per block, blockDim.x == O (64 or 128). Input rows staged in LDS.
// All fp32.
// ---------------------------------------------------------------------------
__global__ void linear_kernel(const float* __restrict__ in, int ld_in,
                              const float* __restrict__ W,
                              const float* __restrict__ bias,
                              float* __restrict__ out, int ld_out,
                              int K, int O, int do_relu)
{
    __shared__ float s_in[4 * 256];   // max K = 256
    const int row0 = blockIdx.x * 4;
    const int o = threadIdx.x;

    for (int idx = threadIdx.x; idx < 4 * K; idx += O) {
        int r = idx / K;
        int k = idx - r * K;
        s_in[idx] = in[(size_t)(row0 + r) * ld_in + k];
    }
    __syncthreads();

    float b = bias ? bias[o] : 0.0f;
    float a0 = b, a1 = b, a2 = b, a3 = b;
    #pragma unroll 4
    for (int k = 0; k < K; ++k) {
        float w = W[(size_t)k * O + o];
        a0 = fmaf(s_in[k],          w, a0);
        a1 = fmaf(s_in[K + k],      w, a1);
        a2 = fmaf(s_in[2 * K + k],  w, a2);
        a3 = fmaf(s_in[3 * K + k],  w, a3);
    }
    if (do_relu) {
        a0 = fmaxf(a0, 0.0f); a1 = fmaxf(a1, 0.0f);
        a2 = fmaxf(a2, 0.0f); a3 = fmaxf(a3, 0.0f);
    }
    out[(size_t)(row0 + 0) * ld_out + o] = a0;
    out[(size_t)(row0 + 1) * ld_out + o] = a1;
    out[(size_t)(row0 + 2) * ld_out + o] = a2;
    out[(size_t)(row0 + 3) * ld_out + o] = a3;
}

// ---------------------------------------------------------------------------
// Scan one adjacency row (fp32 0/1 values): extract nonzero column indices
// into a compact edge list, compute dinv = rsqrt(deg) with deg = nnz + 1
// (self loop from A+I). One block per row; 256 threads x 16 x float4 loads.
// This streams the 1.07 GB adjacency — the HBM-bound term (~170 us floor).
// ---------------------------------------------------------------------------
__global__ void scan_adj_kernel(const float* __restrict__ adj,
                                int* __restrict__ edges,
                                int* __restrict__ cnts,
                                float* __restrict__ dinv)
{
    __shared__ int s_cnt;
    __shared__ int s_list[EDGE_CAP];
    const int row = blockIdx.x;
    if (threadIdx.x == 0) s_cnt = 0;
    __syncthreads();

    const float4* rp = reinterpret_cast<const float4*>(adj + (size_t)row * N_NODES);
    #pragma unroll
    for (int it = 0; it < (N_NODES / 4) / 256; ++it) {   // 16 iters
        int vi = it * 256 + threadIdx.x;
        float4 v = rp[vi];
        int base = vi * 4;
        if (v.x != 0.0f) { int p = atomicAdd(&s_cnt, 1); if (p < EDGE_CAP) s_list[p] = base + 0; }
        if (v.y != 0.0f) { int p = atomicAdd(&s_cnt, 1); if (p < EDGE_CAP) s_list[p] = base + 1; }
        if (v.z != 0.0f) { int p = atomicAdd(&s_cnt, 1); if (p < EDGE_CAP) s_list[p] = base + 2; }
        if (v.w != 0.0f) { int p = atomicAdd(&s_cnt, 1); if (p < EDGE_CAP) s_list[p] = base + 3; }
    }
    __syncthreads();
    int c = s_cnt;
    if (c > EDGE_CAP) c = EDGE_CAP;   // max expected degree ~105 << 256
    for (int k = threadIdx.x; k < c; k += 256)
        edges[(size_t)row * EDGE_CAP + k] = s_list[k];
    if (threadIdx.x == 0) {
        cnts[row] = c;
        dinv[row] = rsqrtf((float)c + 1.0f);
    }
}

// ---------------------------------------------------------------------------
// SpMM + GCN normalization: xg[i,:] = relu(dinv_i * (sum_{j in N(i) u {i}}
// dinv_j * hw[j,:]) + bg). One block (128 threads = features) per row.
// hw is 8 MB -> L2/LLC resident for the gathers.
// ---------------------------------------------------------------------------
__global__ void spmm_kernel(const float* __restrict__ hw,
                            const int* __restrict__ edges,
                            const int* __restrict__ cnts,
                            const float* __restrict__ dinv,
                            const float* __restrict__ bg,
                            float* __restrict__ xg)
{
    __shared__ int   s_e[EDGE_CAP];
    __shared__ float s_d[EDGE_CAP];
    const int row = blockIdx.x;
    const int f = threadIdx.x;      // 0..127
    const int c = cnts[row];

    for (int k = threadIdx.x; k < c; k += 128) {
        int j = edges[(size_t)row * EDGE_CAP + k];
        s_e[k] = j;
        s_d[k] = dinv[j];
    }
    __syncthreads();

    float di = dinv[row];
    float acc = di * hw[(size_t)row * 128 + f];  // self loop
    for (int k = 0; k < c; ++k)
        acc = fmaf(s_d[k], hw[(size_t)s_e[k] * 128 + f], acc);

    float r = fmaf(di, acc, bg[f]);
    xg[(size_t)row * 128 + f] = fmaxf(r, 0.0f);
}

// ---------------------------------------------------------------------------
// Final head: out[i,:] = p2[i,:] @ wo + bo   ([N,64] x [64,5]), fp32 out.
// ---------------------------------------------------------------------------
__global__ void final_kernel(const float* __restrict__ p2,
                             const float* __restrict__ wo,
                             const float* __restrict__ bo,
                             float* __restrict__ out)
{
    __shared__ float s_w[64 * 5];
    __shared__ float s_b[5];
    for (int idx = threadIdx.x; idx < 320; idx += 256) s_w[idx] = wo[idx];
    if (threadIdx.x < 5) s_b[threadIdx.x] = bo[threadIdx.x];
    __syncthreads();

    int i = blockIdx.x * 256 + threadIdx.x;
    float acc[5];
    #pragma unroll
    for (int a = 0; a < 5; ++a) acc[a] = s_b[a];
    #pragma unroll 8
    for (int k = 0; k < 64; ++k) {
        float v = p2[(size_t)i * 64 + k];
        #pragma unroll
        for (int a = 0; a < 5; ++a) acc[a] = fmaf(v, s_w[k * 5 + a], acc[a]);
    }
    #pragma unroll
    for (int a = 0; a < 5; ++a)
        out[(size_t)i * 5 + a] = acc[a];
}

extern "C" void kernel_launch(void* const* d_in, const int* in_sizes, int n_in,
                              void* d_out, int out_size, void* d_ws, size_t ws_size,
                              hipStream_t stream)
{
    const float* x   = (const float*)d_in[0];
    const float* adj = (const float*)d_in[1];
    const float* w1  = (const float*)d_in[2];
    const float* b1  = (const float*)d_in[3];
    const float* w2  = (const float*)d_in[4];
    const float* b2  = (const float*)d_in[5];
    const float* wg  = (const float*)d_in[6];
    const float* bg  = (const float*)d_in[7];
    const float* wd  = (const float*)d_in[8];
    const float* bd  = (const float*)d_in[9];
    const float* wp1 = (const float*)d_in[10];
    const float* bp1 = (const float*)d_in[11];
    const float* wp2 = (const float*)d_in[12];
    const float* bp2 = (const float*)d_in[13];
    const float* wo  = (const float*)d_in[14];
    const float* bo  = (const float*)d_in[15];
    float* out = (float*)d_out;

    char* base = (char*)d_ws;
    // ws layout (52.13 MB):
    float* h1   = (float*)(base);                                  //  4 MB [N,64]
    float* f    = (float*)(base + (4ull  << 20));                  // 16 MB [N,256] concat buf
    float* hw   = (float*)(base + (20ull << 20));                  //  8 MB [N,128]
    float* xg   = (float*)(base + (28ull << 20));                  //  8 MB [N,128]
    float* dinv = (float*)(base + (36ull << 20));                  // 64 KB
    int*   cnts = (int*)  (base + (36ull << 20) + (64ull << 10));  // 64 KB
    int*   edges= (int*)  (base + (36ull << 20) + (128ull << 10)); // 16 MB [N,256]
    float* p1 = xg;   // reuse after xg consumed
    float* p2 = h1;   // reuse after h1 consumed

    const int NB4 = N_NODES / 4;

    // Encoder: h1 = relu(x@w1+b1); h = relu(h1@w2+b2) -> f[:,128:256]; hw = h@wg
    linear_kernel<<<NB4, 64, 0, stream>>>(x, 32, w1, b1, h1, 64, 32, 64, 1);
    linear_kernel<<<NB4, 128, 0, stream>>>(h1, 64, w2, b2, f + 128, 256, 64, 128, 1);
    linear_kernel<<<NB4, 128, 0, stream>>>(f + 128, 256, wg, nullptr, hw, 128, 128, 128, 0);

    // Adjacency scan (dominant HBM read: 1.07 GB) + GCN aggregation
    scan_adj_kernel<<<N_NODES, 256, 0, stream>>>(adj, edges, cnts, dinv);
    spmm_kernel<<<N_NODES, 128, 0, stream>>>(hw, edges, cnts, dinv, bg, xg);

    // xd = relu(xg@wd+bd) -> f[:,0:128]; p1 = relu(f@wp1+bp1); p2 = relu(p1@wp2+bp2)
    linear_kernel<<<NB4, 128, 0, stream>>>(xg, 128, wd, bd, f, 256, 128, 128, 1);
    linear_kernel<<<NB4, 128, 0, stream>>>(f, 256, wp1, bp1, p1, 128, 256, 128, 1);
    linear_kernel<<<NB4, 64, 0, stream>>>(p1, 128, wp2, bp2, p2, 64, 128, 64, 1);

    // out = p2@wo + bo  (fp32)
    final_kernel<<<N_NODES / 256, 256, 0, stream>>>(p2, wo, bo, out);
}

// Round 3
// 1460.734 us; speedup vs baseline: 1.0322x; 1.0322x over previous
//
#include <hip/hip_runtime.h>
#include <hip/hip_bf16.h>

#define N_NODES 16384
#define EDGE_CAP 128   // max expected degree ~97 (mean 65.5, sd 8.1; >7 sigma headroom)

// ---------------------------------------------------------------------------
// Generic linear layer: out[r, o] = act(sum_k in[r, k] * W[k, o] + b[o])
// 4 rows per block, blockDim.x == O (64 or 128). Input rows staged in LDS.
// ---------------------------------------------------------------------------
__global__ void linear_kernel(const float* __restrict__ in, int ld_in,
                              const float* __restrict__ W,
                              const float* __restrict__ bias,
                              float* __restrict__ out, int ld_out,
                              int K, int O, int do_relu)
{
    __shared__ float s_in[4 * 256];   // max K = 256
    const int row0 = blockIdx.x * 4;
    const int o = threadIdx.x;

    for (int idx = threadIdx.x; idx < 4 * K; idx += O) {
        int r = idx / K;
        int k = idx - r * K;
        s_in[idx] = in[(size_t)(row0 + r) * ld_in + k];
    }
    __syncthreads();

    float b = bias ? bias[o] : 0.0f;
    float a0 = b, a1 = b, a2 = b, a3 = b;
    #pragma unroll 4
    for (int k = 0; k < K; ++k) {
        float w = W[(size_t)k * O + o];
        a0 = fmaf(s_in[k],          w, a0);
        a1 = fmaf(s_in[K + k],      w, a1);
        a2 = fmaf(s_in[2 * K + k],  w, a2);
        a3 = fmaf(s_in[3 * K + k],  w, a3);
    }
    if (do_relu) {
        a0 = fmaxf(a0, 0.0f); a1 = fmaxf(a1, 0.0f);
        a2 = fmaxf(a2, 0.0f); a3 = fmaxf(a3, 0.0f);
    }
    out[(size_t)(row0 + 0) * ld_out + o] = a0;
    out[(size_t)(row0 + 1) * ld_out + o] = a1;
    out[(size_t)(row0 + 2) * ld_out + o] = a2;
    out[(size_t)(row0 + 3) * ld_out + o] = a3;
}

// ---------------------------------------------------------------------------
// Zero the per-row edge counters (ws is poisoned 0xAA, must init ourselves).
// ---------------------------------------------------------------------------
__global__ void zero_cnts_kernel(int* __restrict__ cnts)
{
    int i = blockIdx.x * 256 + threadIdx.x;
    if (i < N_NODES) cnts[i] = 0;
}

// ---------------------------------------------------------------------------
// Upper-triangle adjacency scan (adj is symmetric, zero diagonal): block i
// scans columns j > i only — HALF the HBM read of a full scan (537 MB vs
// 1.07 GB). Each edge (i,j) is scattered into both rows' edge lists via
// global atomics on cnts. Natural dispatch order puts the longest rows
// (small i) first — good load balance across 16384 blocks.
// ---------------------------------------------------------------------------
__device__ inline void add_edge(int i, int j,
                                int* __restrict__ edges, int* __restrict__ cnts)
{
    int pi = atomicAdd(&cnts[i], 1);
    if (pi < EDGE_CAP) edges[(size_t)i * EDGE_CAP + pi] = j;
    int pj = atomicAdd(&cnts[j], 1);
    if (pj < EDGE_CAP) edges[(size_t)j * EDGE_CAP + pj] = i;
}

__global__ void tri_scan_kernel(const float* __restrict__ adj,
                                int* __restrict__ edges,
                                int* __restrict__ cnts)
{
    const int i = blockIdx.x;
    const float4* rp = reinterpret_cast<const float4*>(adj + (size_t)i * N_NODES);
    const int v0 = (i + 1) >> 2;     // first float4 that can contain j > i
    for (int vi = v0 + threadIdx.x; vi < N_NODES / 4; vi += 256) {
        float4 v = rp[vi];
        int base = vi * 4;
        if (v.x != 0.0f && base + 0 > i) add_edge(i, base + 0, edges, cnts);
        if (v.y != 0.0f && base + 1 > i) add_edge(i, base + 1, edges, cnts);
        if (v.z != 0.0f && base + 2 > i) add_edge(i, base + 2, edges, cnts);
        if (v.w != 0.0f && base + 3 > i) add_edge(i, base + 3, edges, cnts);
    }
}

// ---------------------------------------------------------------------------
// SpMM + GCN normalization: xg[i,:] = relu(dinv_i * (sum_{j in N(i) u {i}}
// dinv_j * hw[j,:]) + bg), dinv_k = rsqrt(deg_k), deg_k = cnt_k + 1 (A+I).
// One block (128 threads = features) per row; hw (8 MB) is L2/LLC resident.
// ---------------------------------------------------------------------------
__global__ void spmm_kernel(const float* __restrict__ hw,
                            const int* __restrict__ edges,
                            const int* __restrict__ cnts,
                            const float* __restrict__ bg,
                            float* __restrict__ xg)
{
    __shared__ int   s_e[EDGE_CAP];
    __shared__ float s_d[EDGE_CAP];
    const int row = blockIdx.x;
    const int f = threadIdx.x;      // 0..127
    int c = cnts[row];
    if (c > EDGE_CAP) c = EDGE_CAP; // statistically impossible

    if (threadIdx.x < c) {          // c <= 128 == blockDim.x: one pass
        int j = edges[(size_t)row * EDGE_CAP + threadIdx.x];
        s_e[threadIdx.x] = j;
        s_d[threadIdx.x] = rsqrtf((float)cnts[j] + 1.0f);
    }
    __syncthreads();

    float di = rsqrtf((float)c + 1.0f);
    float acc = di * hw[(size_t)row * 128 + f];  // self loop
    for (int k = 0; k < c; ++k)
        acc = fmaf(s_d[k], hw[(size_t)s_e[k] * 128 + f], acc);

    float r = fmaf(di, acc, bg[f]);
    xg[(size_t)row * 128 + f] = fmaxf(r, 0.0f);
}

// ---------------------------------------------------------------------------
// Final head: out[i,:] = p2[i,:] @ wo + bo   ([N,64] x [64,5]), fp32 out.
// ---------------------------------------------------------------------------
__global__ void final_kernel(const float* __restrict__ p2,
                             const float* __restrict__ wo,
                             const float* __restrict__ bo,
                             float* __restrict__ out)
{
    __shared__ float s_w[64 * 5];
    __shared__ float s_b[5];
    for (int idx = threadIdx.x; idx < 320; idx += 256) s_w[idx] = wo[idx];
    if (threadIdx.x < 5) s_b[threadIdx.x] = bo[threadIdx.x];
    __syncthreads();

    int i = blockIdx.x * 256 + threadIdx.x;
    float acc[5];
    #pragma unroll
    for (int a = 0; a < 5; ++a) acc[a] = s_b[a];
    #pragma unroll 8
    for (int k = 0; k < 64; ++k) {
        float v = p2[(size_t)i * 64 + k];
        #pragma unroll
        for (int a = 0; a < 5; ++a) acc[a] = fmaf(v, s_w[k * 5 + a], acc[a]);
    }
    #pragma unroll
    for (int a = 0; a < 5; ++a)
        out[(size_t)i * 5 + a] = acc[a];
}

extern "C" void kernel_launch(void* const* d_in, const int* in_sizes, int n_in,
                              void* d_out, int out_size, void* d_ws, size_t ws_size,
                              hipStream_t stream)
{
    const float* x   = (const float*)d_in[0];
    const float* adj = (const float*)d_in[1];
    const float* w1  = (const float*)d_in[2];
    const float* b1  = (const float*)d_in[3];
    const float* w2  = (const float*)d_in[4];
    const float* b2  = (const float*)d_in[5];
    const float* wg  = (const float*)d_in[6];
    const float* bg  = (const float*)d_in[7];
    const float* wd  = (const float*)d_in[8];
    const float* bd  = (const float*)d_in[9];
    const float* wp1 = (const float*)d_in[10];
    const float* bp1 = (const float*)d_in[11];
    const float* wp2 = (const float*)d_in[12];
    const float* bp2 = (const float*)d_in[13];
    const float* wo  = (const float*)d_in[14];
    const float* bo  = (const float*)d_in[15];
    float* out = (float*)d_out;

    char* base = (char*)d_ws;
    // ws layout (~44.2 MB):
    float* h1   = (float*)(base);                                  //  4 MB [N,64]
    float* f    = (float*)(base + (4ull  << 20));                  // 16 MB [N,256] concat buf
    float* hw   = (float*)(base + (20ull << 20));                  //  8 MB [N,128]
    float* xg   = (float*)(base + (28ull << 20));                  //  8 MB [N,128]
    int*   cnts = (int*)  (base + (36ull << 20));                  // 64 KB
    int*   edges= (int*)  (base + (36ull << 20) + (64ull << 10));  //  8 MB [N,128]
    float* p1 = xg;   // reuse after xg consumed
    float* p2 = h1;   // reuse after h1 consumed

    const int NB4 = N_NODES / 4;

    // Edge counters must start at 0 (ws arrives poisoned 0xAA).
    zero_cnts_kernel<<<N_NODES / 256, 256, 0, stream>>>(cnts);

    // Encoder: h1 = relu(x@w1+b1); h = relu(h1@w2+b2) -> f[:,128:256]; hw = h@wg
    linear_kernel<<<NB4, 64, 0, stream>>>(x, 32, w1, b1, h1, 64, 32, 64, 1);
    linear_kernel<<<NB4, 128, 0, stream>>>(h1, 64, w2, b2, f + 128, 256, 64, 128, 1);
    linear_kernel<<<NB4, 128, 0, stream>>>(f + 128, 256, wg, nullptr, hw, 128, 128, 128, 0);

    // Upper-triangle adjacency scan (537 MB HBM read) + GCN aggregation
    tri_scan_kernel<<<N_NODES, 256, 0, stream>>>(adj, edges, cnts);
    spmm_kernel<<<N_NODES, 128, 0, stream>>>(hw, edges, cnts, bg, xg);

    // xd = relu(xg@wd+bd) -> f[:,0:128]; p1 = relu(f@wp1+bp1); p2 = relu(p1@wp2+bp2)
    linear_kernel<<<NB4, 128, 0, stream>>>(xg, 128, wd, bd, f, 256, 128, 128, 1);
    linear_kernel<<<NB4, 128, 0, stream>>>(f, 256, wp1, bp1, p1, 128, 256, 128, 1);
    linear_kernel<<<NB4, 64, 0, stream>>>(p1, 128, wp2, bp2, p2, 64, 128, 64, 1);

    // out = p2@wo + bo  (fp32)
    final_kernel<<<N_NODES / 256, 256, 0, stream>>>(p2, wo, bo, out);
}

// Round 4
// 1420.398 us; speedup vs baseline: 1.0615x; 1.0284x over previous
//
#include <hip/hip_runtime.h>
#include <hip/hip_bf16.h>

#define N_NODES 16384
#define EDGE_CAP 128   // max expected degree ~97 (mean 65.5, sd 8.1; >7 sigma headroom)

// ---------------------------------------------------------------------------
// Generic linear layer: out[r, o] = act(sum_k in[r, k] * W[k, o] + b[o])
// 4 rows per block, blockDim.x == O (64 or 128). Input rows staged in LDS.
// ---------------------------------------------------------------------------
__global__ void linear_kernel(const float* __restrict__ in, int ld_in,
                              const float* __restrict__ W,
                              const float* __restrict__ bias,
                              float* __restrict__ out, int ld_out,
                              int K, int O, int do_relu)
{
    __shared__ float s_in[4 * 128];
    const int row0 = blockIdx.x * 4;
    const int o = threadIdx.x;

    for (int idx = threadIdx.x; idx < 4 * K; idx += O) {
        int r = idx / K;
        int k = idx - r * K;
        s_in[idx] = in[(size_t)(row0 + r) * ld_in + k];
    }
    __syncthreads();

    float b = bias ? bias[o] : 0.0f;
    float a0 = b, a1 = b, a2 = b, a3 = b;
    #pragma unroll 4
    for (int k = 0; k < K; ++k) {
        float w = W[(size_t)k * O + o];
        a0 = fmaf(s_in[k],          w, a0);
        a1 = fmaf(s_in[K + k],      w, a1);
        a2 = fmaf(s_in[2 * K + k],  w, a2);
        a3 = fmaf(s_in[3 * K + k],  w, a3);
    }
    if (do_relu) {
        a0 = fmaxf(a0, 0.0f); a1 = fmaxf(a1, 0.0f);
        a2 = fmaxf(a2, 0.0f); a3 = fmaxf(a3, 0.0f);
    }
    out[(size_t)(row0 + 0) * ld_out + o] = a0;
    out[(size_t)(row0 + 1) * ld_out + o] = a1;
    out[(size_t)(row0 + 2) * ld_out + o] = a2;
    out[(size_t)(row0 + 3) * ld_out + o] = a3;
}

// ---------------------------------------------------------------------------
// Zero the per-row edge counters (ws arrives poisoned 0xAA).
// ---------------------------------------------------------------------------
__global__ void zero_cnts_kernel(int* __restrict__ cnts)
{
    int i = blockIdx.x * 256 + threadIdx.x;
    if (i < N_NODES) cnts[i] = 0;
}

// ---------------------------------------------------------------------------
// Upper-triangle adjacency scan (adj symmetric, zero diagonal): block i scans
// columns j > i only (537 MB HBM read — the irreducible term). Row-i-side
// edges are aggregated in LDS and flushed with ONE base-reservation atomic +
// coalesced writes; only the j-side needs a per-edge global atomic + 4 B
// scattered write. Halves global atomics vs the naive both-sides scatter.
// ---------------------------------------------------------------------------
__global__ void tri_scan_kernel(const float* __restrict__ adj,
                                int* __restrict__ edges,
                                int* __restrict__ cnts)
{
    __shared__ int s_cnt;
    __shared__ int s_base;
    __shared__ int s_list[EDGE_CAP];
    const int i = blockIdx.x;
    if (threadIdx.x == 0) s_cnt = 0;
    __syncthreads();

    const float4* rp = reinterpret_cast<const float4*>(adj + (size_t)i * N_NODES);
    const int v0 = (i + 1) >> 2;     // first float4 that can contain j > i
    for (int vi = v0 + threadIdx.x; vi < N_NODES / 4; vi += 256) {
        float4 v = rp[vi];
        int base = vi * 4;
        float c0 = v.x, c1 = v.y, c2 = v.z, c3 = v.w;
        #pragma unroll
        for (int q = 0; q < 4; ++q) {
            float val = (q == 0) ? c0 : (q == 1) ? c1 : (q == 2) ? c2 : c3;
            int j = base + q;
            if (val != 0.0f && j > i) {
                int p = atomicAdd(&s_cnt, 1);            // row-i side: LDS
                if (p < EDGE_CAP) s_list[p] = j;
                int pj = atomicAdd(&cnts[j], 1);         // row-j side: global
                if (pj < EDGE_CAP) edges[(size_t)j * EDGE_CAP + pj] = i;
            }
        }
    }
    __syncthreads();
    int c = s_cnt;
    if (c > EDGE_CAP) c = EDGE_CAP;                      // statistically impossible
    if (threadIdx.x == 0) s_base = atomicAdd(&cnts[i], c);
    __syncthreads();
    const int b = s_base;
    for (int k = threadIdx.x; k < c; k += 256) {
        int pos = b + k;
        if (pos < EDGE_CAP) edges[(size_t)i * EDGE_CAP + pos] = s_list[k];
    }
}

// ---------------------------------------------------------------------------
// SpMM + GCN normalization: xg[i,:] = relu(dinv_i * (sum_{j in N(i) u {i}}
// dinv_j * hw[j,:]) + bg), dinv_k = rsqrt(cnt_k + 1)  (A+I self loop).
// One block (128 threads = features) per row; hw (8 MB) is L2/LLC resident.
// ---------------------------------------------------------------------------
__global__ void spmm_kernel(const float* __restrict__ hw,
                            const int* __restrict__ edges,
                            const int* __restrict__ cnts,
                            const float* __restrict__ bg,
                            float* __restrict__ xg)
{
    __shared__ int   s_e[EDGE_CAP];
    __shared__ float s_d[EDGE_CAP];
    const int row = blockIdx.x;
    const int f = threadIdx.x;      // 0..127
    int c = cnts[row];
    if (c > EDGE_CAP) c = EDGE_CAP;

    if (threadIdx.x < c) {          // c <= 128 == blockDim.x: one pass
        int j = edges[(size_t)row * EDGE_CAP + threadIdx.x];
        s_e[threadIdx.x] = j;
        s_d[threadIdx.x] = rsqrtf((float)cnts[j] + 1.0f);
    }
    __syncthreads();

    float di = rsqrtf((float)c + 1.0f);
    float acc = di * hw[(size_t)row * 128 + f];  // self loop
    for (int k = 0; k < c; ++k)
        acc = fmaf(s_d[k], hw[(size_t)s_e[k] * 128 + f], acc);

    float r = fmaf(di, acc, bg[f]);
    xg[(size_t)row * 128 + f] = fmaxf(r, 0.0f);
}

// ---------------------------------------------------------------------------
// Fused tail: per block of 4 rows (128 threads), entirely in LDS:
//   xd = relu(xg@wd+bd); p1 = relu([xd,h]@wp1+bp1); p2 = relu(p1@wp2+bp2);
//   out = p2@wo + bo.
// Eliminates 3 launches and ~36 MB of global activation round-trips.
// ---------------------------------------------------------------------------
__global__ void tail_kernel(const float* __restrict__ xg,
                            const float* __restrict__ h,
                            const float* __restrict__ wd,  const float* __restrict__ bd,
                            const float* __restrict__ wp1, const float* __restrict__ bp1,
                            const float* __restrict__ wp2, const float* __restrict__ bp2,
                            const float* __restrict__ wo,  const float* __restrict__ bo,
                            float* __restrict__ out)
{
    __shared__ float s_a[4 * 128];   // xg, then p1
    __shared__ float s_h[4 * 128];   // h
    __shared__ float s_b[4 * 128];   // xd, then p2 (uses first 4*64)
    const int row0 = blockIdx.x * 4;
    const int tid = threadIdx.x;     // 0..127

    for (int idx = tid; idx < 512; idx += 128) {
        int r = idx >> 7, k = idx & 127;
        s_a[idx] = xg[(size_t)(row0 + r) * 128 + k];
        s_h[idx] = h [(size_t)(row0 + r) * 128 + k];
    }
    __syncthreads();

    // xd = relu(xg @ wd + bd)  -> s_b
    {
        const int o = tid;
        float b = bd[o];
        float a0 = b, a1 = b, a2 = b, a3 = b;
        #pragma unroll 4
        for (int k = 0; k < 128; ++k) {
            float w = wd[(size_t)k * 128 + o];
            a0 = fmaf(s_a[k],       w, a0);
            a1 = fmaf(s_a[128 + k], w, a1);
            a2 = fmaf(s_a[256 + k], w, a2);
            a3 = fmaf(s_a[384 + k], w, a3);
        }
        __syncthreads();             // all reads of s_a (xg) done
        s_b[o]       = fmaxf(a0, 0.0f);
        s_b[128 + o] = fmaxf(a1, 0.0f);
        s_b[256 + o] = fmaxf(a2, 0.0f);
        s_b[384 + o] = fmaxf(a3, 0.0f);
    }
    __syncthreads();

    // p1 = relu([xd, h] @ wp1 + bp1)  -> s_a
    {
        const int o = tid;
        float b = bp1[o];
        float a0 = b, a1 = b, a2 = b, a3 = b;
        #pragma unroll 4
        for (int k = 0; k < 128; ++k) {
            float w = wp1[(size_t)k * 128 + o];          // xd half
            a0 = fmaf(s_b[k],       w, a0);
            a1 = fmaf(s_b[128 + k], w, a1);
            a2 = fmaf(s_b[256 + k], w, a2);
            a3 = fmaf(s_b[384 + k], w, a3);
        }
        #pragma unroll 4
        for (int k = 0; k < 128; ++k) {
            float w = wp1[(size_t)(128 + k) * 128 + o];  // h half
            a0 = fmaf(s_h[k],       w, a0);
            a1 = fmaf(s_h[128 + k], w, a1);
            a2 = fmaf(s_h[256 + k], w, a2);
            a3 = fmaf(s_h[384 + k], w, a3);
        }
        s_a[o]       = fmaxf(a0, 0.0f);
        s_a[128 + o] = fmaxf(a1, 0.0f);
        s_a[256 + o] = fmaxf(a2, 0.0f);
        s_a[384 + o] = fmaxf(a3, 0.0f);
    }
    __syncthreads();

    // p2 = relu(p1 @ wp2 + bp2), O=64 -> s_b[0:256]
    // threads 0..63 handle rows 0,1; threads 64..127 handle rows 2,3
    {
        const int o  = tid & 63;
        const int rp = (tid >> 6) * 2;
        float b = bp2[o];
        float a0 = b, a1 = b;
        #pragma unroll 4
        for (int k = 0; k < 128; ++k) {
            float w = wp2[(size_t)k * 64 + o];
            a0 = fmaf(s_a[rp * 128 + k],       w, a0);
            a1 = fmaf(s_a[(rp + 1) * 128 + k], w, a1);
        }
        __syncthreads();             // all reads of s_b (xd) done
        s_b[rp * 64 + o]       = fmaxf(a0, 0.0f);
        s_b[(rp + 1) * 64 + o] = fmaxf(a1, 0.0f);
    }
    __syncthreads();

    // out = p2 @ wo + bo, O=5 (threads 0..19: r=tid/5, a=tid%5)
    if (tid < 20) {
        const int r = tid / 5, a = tid - r * 5;
        float acc = bo[a];
        #pragma unroll 8
        for (int k = 0; k < 64; ++k)
            acc = fmaf(s_b[r * 64 + k], wo[k * 5 + a], acc);
        out[(size_t)(row0 + r) * 5 + a] = acc;
    }
}

extern "C" void kernel_launch(void* const* d_in, const int* in_sizes, int n_in,
                              void* d_out, int out_size, void* d_ws, size_t ws_size,
                              hipStream_t stream)
{
    const float* x   = (const float*)d_in[0];
    const float* adj = (const float*)d_in[1];
    const float* w1  = (const float*)d_in[2];
    const float* b1  = (const float*)d_in[3];
    const float* w2  = (const float*)d_in[4];
    const float* b2  = (const float*)d_in[5];
    const float* wg  = (const float*)d_in[6];
    const float* bg  = (const float*)d_in[7];
    const float* wd  = (const float*)d_in[8];
    const float* bd  = (const float*)d_in[9];
    const float* wp1 = (const float*)d_in[10];
    const float* bp1 = (const float*)d_in[11];
    const float* wp2 = (const float*)d_in[12];
    const float* bp2 = (const float*)d_in[13];
    const float* wo  = (const float*)d_in[14];
    const float* bo  = (const float*)d_in[15];
    float* out = (float*)d_out;

    char* base = (char*)d_ws;
    // ws layout (~36.1 MB):
    float* h1   = (float*)(base);                                  //  4 MB [N,64]
    float* h    = (float*)(base + (4ull  << 20));                  //  8 MB [N,128]
    float* hw   = (float*)(base + (12ull << 20));                  //  8 MB [N,128]
    float* xg   = (float*)(base + (20ull << 20));                  //  8 MB [N,128]
    int*   cnts = (int*)  (base + (28ull << 20));                  // 64 KB
    int*   edges= (int*)  (base + (28ull << 20) + (64ull << 10));  //  8 MB [N,128]

    const int NB4 = N_NODES / 4;

    // Edge counters must start at 0 (ws arrives poisoned 0xAA).
    zero_cnts_kernel<<<N_NODES / 256, 256, 0, stream>>>(cnts);

    // Encoder: h1 = relu(x@w1+b1); h = relu(h1@w2+b2); hw = h@wg
    linear_kernel<<<NB4, 64, 0, stream>>>(x, 32, w1, b1, h1, 64, 32, 64, 1);
    linear_kernel<<<NB4, 128, 0, stream>>>(h1, 64, w2, b2, h, 128, 64, 128, 1);
    linear_kernel<<<NB4, 128, 0, stream>>>(h, 128, wg, nullptr, hw, 128, 128, 128, 0);

    // Upper-triangle adjacency scan (537 MB HBM read) + GCN aggregation
    tri_scan_kernel<<<N_NODES, 256, 0, stream>>>(adj, edges, cnts);
    spmm_kernel<<<N_NODES, 128, 0, stream>>>(hw, edges, cnts, bg, xg);

    // Fused tail: xd -> p1 -> p2 -> out
    tail_kernel<<<NB4, 128, 0, stream>>>(xg, h, wd, bd, wp1, bp1, wp2, bp2,
                                         wo, bo, out);
}